// Round 1
// baseline (1231.786 us; speedup 1.0000x reference)
//
#include <hip/hip_runtime.h>
#include <hip/hip_bf16.h>

typedef unsigned short u16;
typedef unsigned int u32;
typedef __attribute__((ext_vector_type(4))) float fx4;
typedef __attribute__((ext_vector_type(8))) __bf16 bf8;

#define NEGV -1e9f
#define SCALE_ 0.17677669529663687f

static __device__ __forceinline__ u16 f2bu(float f){
    __hip_bfloat16 h = __float2bfloat16(f);
    return *reinterpret_cast<u16*>(&h);
}

// ---- K0: fp32 -> bf16 conversion ----
__global__ void f2b_kernel(const float* __restrict__ src, u16* __restrict__ dst, int n){
    int i = blockIdx.x*256 + threadIdx.x;
    if (i < n) dst[i] = f2bu(src[i]);
}

// ---- K1: roll(-3,-3) + window partition: x[64,192,56,56] -> xw[200704,192] ----
__global__ __launch_bounds__(256) void partition_kernel(const float* __restrict__ x, float* __restrict__ xw){
    __shared__ float lds[192*57];
    const int bi = blockIdx.x;          // b*56 + i (output row)
    const int b = bi/56, i = bi%56;
    const int si = (i+3)%56;            // source row after roll
    const float* src = x + (size_t)b*602112 + (size_t)si*56;
    for (int e = threadIdx.x; e < 10752; e += 256){
        int c = e/56, j = e%56;
        lds[c*57 + j] = src[(size_t)c*3136 + j];
    }
    __syncthreads();
    const int wrow_base = (b*8 + i/7)*8;
    const int prow = (i%7)*7;
    for (int e = threadIdx.x; e < 10752; e += 256){
        int j = e/192, c = e%192;       // j = output column
        int t = (wrow_base + j/7)*49 + prow + (j%7);
        xw[(size_t)t*192 + c] = lds[c*57 + (j+3)%56];
    }
}

// ---- K9: window reverse + roll(+3,+3): xw[200704,192] -> out[64,192,56,56] ----
__global__ __launch_bounds__(256) void reverse_kernel(const float* __restrict__ xw, float* __restrict__ out){
    __shared__ float lds[192*57];
    const int bi = blockIdx.x;          // b*56 + h (output row)
    const int b = bi/56, h = bi%56;
    const int i = (h+53)%56;            // source xr row
    const int wrow_base = (b*8 + i/7)*8;
    const int prow = (i%7)*7;
    for (int e = threadIdx.x; e < 10752; e += 256){
        int j = e/192, c = e%192;
        int t = (wrow_base + j/7)*49 + prow + (j%7);
        lds[c*57 + j] = xw[(size_t)t*192 + c];
    }
    __syncthreads();
    float* dst = out + (size_t)b*602112 + (size_t)h*56;
    for (int e = threadIdx.x; e < 10752; e += 256){
        int c = e/56, w = e%56;
        dst[(size_t)c*3136 + w] = lds[c*57 + (w+53)%56];
    }
}

// ---- LN: one wave per token (192 ch), fp32 in, bf16 out ----
__global__ __launch_bounds__(256) void ln_kernel(const float* __restrict__ x, const float* __restrict__ g,
                                                 const float* __restrict__ bta, u16* __restrict__ y){
    const int t = blockIdx.x*4 + (threadIdx.x>>6);
    const int l = threadIdx.x & 63;
    const float* xr = x + (size_t)t*192;
    float v0 = xr[l], v1 = xr[l+64], v2 = xr[l+128];
    float s = v0+v1+v2;
    #pragma unroll
    for (int o=32;o;o>>=1) s += __shfl_xor(s, o, 64);
    const float mean = s*(1.f/192.f);
    float d0 = v0-mean, d1 = v1-mean, d2 = v2-mean;
    float q = d0*d0 + d1*d1 + d2*d2;
    #pragma unroll
    for (int o=32;o;o>>=1) q += __shfl_xor(q, o, 64);
    const float rstd = rsqrtf(q*(1.f/192.f) + 1e-5f);
    u16* yr = y + (size_t)t*192;
    yr[l]     = f2bu(d0*rstd*g[l]     + bta[l]);
    yr[l+64]  = f2bu(d1*rstd*g[l+64]  + bta[l+64]);
    yr[l+128] = f2bu(d2*rstd*g[l+128] + bta[l+128]);
}

// ---- generic GEMM: out[M,N] = epilogue(A[M,K](bf16) @ Bw[N,K]^T(bf16)) ----
// ACT: 1=exact gelu. RES: add fp32 residual. OUTBF: 1=bf16 out else fp32. HASB: bias[N].
template<int ACT, int RES, int OUTBF, int HASB>
__global__ __launch_bounds__(256) void gemm_kernel(
    const u16* __restrict__ A, const u16* __restrict__ Bw,
    const float* __restrict__ bias, const float* res, void* out,
    int N, int K)
{
    __shared__ u16 As[64*40];
    __shared__ u16 Bs[64*40];
    const int tid = threadIdx.x;
    const int m0 = blockIdx.x*64, n0 = blockIdx.y*64;
    const int w = tid>>6, l = tid&63;
    const int wm = (w>>1)*32, wn = (w&1)*32;
    const int lr = l&15, lg = l>>4;
    fx4 acc[2][2] = {};
    const int sr = tid>>2, sk = (tid&3)*8;
    const u16* Ap = A + (size_t)(m0+sr)*K + sk;
    const u16* Bp = Bw + (size_t)(n0+sr)*K + sk;
    for (int kt=0; kt<K; kt+=32){
        uint4 av = *(const uint4*)(Ap + kt);
        uint4 bv = *(const uint4*)(Bp + kt);
        *(uint4*)(As + sr*40 + sk) = av;
        *(uint4*)(Bs + sr*40 + sk) = bv;
        __syncthreads();
        bf8 af[2], bf[2];
        #pragma unroll
        for (int r=0;r<2;r++) af[r] = *(const bf8*)(As + (wm + r*16 + lr)*40 + lg*8);
        #pragma unroll
        for (int c=0;c<2;c++) bf[c] = *(const bf8*)(Bs + (wn + c*16 + lr)*40 + lg*8);
        #pragma unroll
        for (int r=0;r<2;r++)
            #pragma unroll
            for (int c=0;c<2;c++)
                acc[r][c] = __builtin_amdgcn_mfma_f32_16x16x32_bf16(af[r], bf[c], acc[r][c], 0,0,0);
        __syncthreads();
    }
    #pragma unroll
    for (int r=0;r<2;r++)
    #pragma unroll
    for (int c=0;c<2;c++){
        const int row0 = m0 + wm + r*16 + lg*4;
        const int col  = n0 + wn + c*16 + lr;
        const float bv = HASB ? bias[col] : 0.f;
        #pragma unroll
        for (int q=0;q<4;q++){
            const size_t idx = (size_t)(row0+q)*N + col;
            float v = acc[r][c][q] + bv;
            if (ACT) v = 0.5f*v*(1.f + erff(v*0.70710678118654752f));
            if (RES) v += res[idx];
            if (OUTBF) ((u16*)out)[idx] = f2bu(v);
            else       ((float*)out)[idx] = v;
        }
    }
}

// ---- attention: one wave per (window, head) ----
__global__ __launch_bounds__(64) void attn_kernel(const u16* __restrict__ qkv,
                                                  const float* __restrict__ rel_table,
                                                  u16* __restrict__ o)
{
    __shared__ u16 pa[64*72];
    __shared__ u16 vt[32*72];
    const int bid = blockIdx.x;
    const int widx = bid/6, h = bid - widx*6;
    const int wi = widx & 63;
    const int nhi = wi>>3, nwi = wi&7;
    const int l = threadIdx.x, lr = l&15, lg = l>>4;
    const u16* base = qkv + (size_t)widx*49*576;

    // Q/K fragments straight from global (clamp pad rows; garbage logits overwritten below)
    bf8 qf[4], kf[4];
    #pragma unroll
    for (int t=0;t<4;t++){
        const int row = min(t*16 + lr, 48);
        qf[t] = *(const bf8*)(base + (size_t)row*576 + h*32 + lg*8);
        kf[t] = *(const bf8*)(base + (size_t)row*576 + 192 + h*32 + lg*8);
    }
    // zero V^T pad columns j in [49,64)
    for (int e=l; e<480; e+=64){
        int d = e/15, j = 49 + (e - d*15);
        vt[d*72 + j] = 0;
    }
    // load V transposed into LDS: vt[d][j] = v[j][d]
    for (int e=l; e<784; e+=64){
        int j = e>>4, dp = e&15;
        u32 val = *(const u32*)(base + (size_t)j*576 + 384 + h*32 + dp*2);
        vt[(dp*2)*72 + j]   = (u16)(val & 0xffffu);
        vt[(dp*2+1)*72 + j] = (u16)(val >> 16);
    }

    // QK^T: 64x64 padded logits
    fx4 acc[4][4] = {};
    #pragma unroll
    for (int ti=0;ti<4;ti++)
        #pragma unroll
        for (int tj=0;tj<4;tj++)
            acc[ti][tj] = __builtin_amdgcn_mfma_f32_16x16x32_bf16(qf[ti], kf[tj], acc[ti][tj], 0,0,0);

    // per-lane column (key) indices
    int jdiv[4], jmod[4], mj[4];
    #pragma unroll
    for (int tj=0;tj<4;tj++){
        const int j = tj*16 + lr;
        if (j < 49){
            const int jd = j/7, jm = j - jd*7;
            jdiv[tj]=jd; jmod[tj]=jm;
            const int gh = nhi*7 + jd, gw = nwi*7 + jm;
            mj[tj] = (gh<49?0:(gh<53?1:2))*3 + (gw<49?0:(gw<53?1:2));
        } else { jdiv[tj]=0; jmod[tj]=0; mj[tj] = -1; }
    }
    // logits = qk*scale + rel_bias + shift_mask; pads -> NEG
    #pragma unroll
    for (int ti=0;ti<4;ti++){
        #pragma unroll
        for (int reg=0;reg<4;reg++){
            const int i = ti*16 + lg*4 + reg;
            int id=0, im=0, mi=-2;
            if (i < 49){
                id = i/7; im = i - id*7;
                const int gh = nhi*7 + id, gw = nwi*7 + im;
                mi = (gh<49?0:(gh<53?1:2))*3 + (gw<49?0:(gw<53?1:2));
            }
            #pragma unroll
            for (int tj=0;tj<4;tj++){
                const int j = tj*16 + lr;
                float lv = NEGV;
                if (i < 49 && j < 49){
                    const int ridx = (id - jdiv[tj] + 6)*13 + (im - jmod[tj] + 6);
                    lv = acc[ti][tj][reg]*SCALE_ + rel_table[ridx*6 + h]
                       + ((mi == mj[tj]) ? 0.f : NEGV);
                }
                acc[ti][tj][reg] = lv;
            }
        }
    }
    // row softmax: row lives in one 16-lane group across 4 tj tiles
    #pragma unroll
    for (int ti=0;ti<4;ti++){
        #pragma unroll
        for (int reg=0;reg<4;reg++){
            float mx = fmaxf(fmaxf(acc[ti][0][reg], acc[ti][1][reg]),
                             fmaxf(acc[ti][2][reg], acc[ti][3][reg]));
            #pragma unroll
            for (int o2=8;o2;o2>>=1) mx = fmaxf(mx, __shfl_xor(mx, o2, 64));
            float sum = 0.f;
            #pragma unroll
            for (int tj=0;tj<4;tj++){
                float p = __expf(acc[ti][tj][reg] - mx);
                acc[ti][tj][reg] = p;
                sum += p;
            }
            #pragma unroll
            for (int o2=8;o2;o2>>=1) sum += __shfl_xor(sum, o2, 64);
            const float rs = 1.f/sum;
            #pragma unroll
            for (int tj=0;tj<4;tj++) acc[ti][tj][reg] *= rs;
        }
    }
    // P -> LDS (bf16)
    #pragma unroll
    for (int ti=0;ti<4;ti++)
        #pragma unroll
        for (int tj=0;tj<4;tj++)
            #pragma unroll
            for (int reg=0;reg<4;reg++)
                pa[(ti*16 + lg*4 + reg)*72 + tj*16 + lr] = f2bu(acc[ti][tj][reg]);
    __syncthreads();

    // PV: o[64x32] = P[64x64] @ V[64x32]
    fx4 oacc[4][2] = {};
    #pragma unroll
    for (int kk=0;kk<2;kk++){
        bf8 bfr[2];
        #pragma unroll
        for (int cd=0;cd<2;cd++)
            bfr[cd] = *(const bf8*)(vt + (cd*16+lr)*72 + kk*32 + lg*8);
        #pragma unroll
        for (int ti=0;ti<4;ti++){
            bf8 afr = *(const bf8*)(pa + (ti*16+lr)*72 + kk*32 + lg*8);
            #pragma unroll
            for (int cd=0;cd<2;cd++)
                oacc[ti][cd] = __builtin_amdgcn_mfma_f32_16x16x32_bf16(afr, bfr[cd], oacc[ti][cd], 0,0,0);
        }
    }
    u16* ob = o + (size_t)widx*49*192 + h*32;
    #pragma unroll
    for (int ti=0;ti<4;ti++)
        #pragma unroll
        for (int cd=0;cd<2;cd++)
            #pragma unroll
            for (int q=0;q<4;q++){
                const int i = ti*16 + lg*4 + q;
                if (i < 49) ob[(size_t)i*192 + cd*16 + lr] = f2bu(oacc[ti][cd][q]);
            }
}

extern "C" void kernel_launch(void* const* d_in, const int* in_sizes, int n_in,
                              void* d_out, int out_size, void* d_ws, size_t ws_size,
                              hipStream_t stream)
{
    const float* x      = (const float*)d_in[0];
    const float* ln1_g  = (const float*)d_in[1];
    const float* ln1_b  = (const float*)d_in[2];
    const float* qkv_w  = (const float*)d_in[3];
    const float* out_w  = (const float*)d_in[4];
    const float* out_b  = (const float*)d_in[5];
    const float* ln2_g  = (const float*)d_in[6];
    const float* ln2_b  = (const float*)d_in[7];
    const float* mlp_w1 = (const float*)d_in[8];
    const float* mlp_b1 = (const float*)d_in[9];
    const float* mlp_w2 = (const float*)d_in[10];
    const float* mlp_b2 = (const float*)d_in[11];
    const float* rel_t  = (const float*)d_in[12];

    char* ws = (char*)d_ws;
    float* Abuf = (float*)ws;                              // [T,192] f32 (xw / xw2 / xw3)
    u16*   Bbuf = (u16*)(ws + 154140672);                  // [T,192] bf16 (y / o / y2)
    u16*   Cbuf = (u16*)(ws + 154140672 + 77070336);       // [T,768] bf16 (qkv / h)
    u16*   Wq = (u16*)(ws + 539492352);
    u16*   Wo = Wq + 110592;
    u16*   W1 = Wo + 36864;
    u16*   W2 = W1 + 147456;

    f2b_kernel<<<(110592+255)/256,256,0,stream>>>(qkv_w, Wq, 110592);
    f2b_kernel<<<(36864+255)/256,256,0,stream>>>(out_w, Wo, 36864);
    f2b_kernel<<<(147456+255)/256,256,0,stream>>>(mlp_w1, W1, 147456);
    f2b_kernel<<<(147456+255)/256,256,0,stream>>>(mlp_w2, W2, 147456);

    partition_kernel<<<3584,256,0,stream>>>(x, Abuf);
    ln_kernel<<<50176,256,0,stream>>>(Abuf, ln1_g, ln1_b, Bbuf);
    // qkv = y @ Wq^T : [T,576] bf16
    gemm_kernel<0,0,1,0><<<dim3(3136,9),256,0,stream>>>(Bbuf, Wq, nullptr, nullptr, Cbuf, 576, 192);
    attn_kernel<<<24576,64,0,stream>>>(Cbuf, rel_t, Bbuf);
    // xw += o @ Wo^T + b : fp32 in-place
    gemm_kernel<0,1,0,1><<<dim3(3136,3),256,0,stream>>>(Bbuf, Wo, out_b, Abuf, Abuf, 192, 192);
    ln_kernel<<<50176,256,0,stream>>>(Abuf, ln2_g, ln2_b, Bbuf);
    // h = gelu(y2 @ W1^T + b1) : [T,768] bf16
    gemm_kernel<1,0,1,1><<<dim3(3136,12),256,0,stream>>>(Bbuf, W1, mlp_b1, nullptr, Cbuf, 768, 192);
    // xw += h @ W2^T + b2 : fp32 in-place
    gemm_kernel<0,1,0,1><<<dim3(3136,3),256,0,stream>>>(Cbuf, W2, mlp_b2, Abuf, Abuf, 192, 768);
    reverse_kernel<<<3584,256,0,stream>>>(Abuf, (float*)d_out);
}